// Round 7
// baseline (333.897 us; speedup 1.0000x reference)
//
#include <hip/hip_runtime.h>
#include <cstddef>

#define NN 8192
#define FD 256
#define LSLOPE 0.01f
#define NEGF -3.0e38f
#define CAP 192          // max nonzeros per row (avg 33, binomial max ~65)

typedef float f4 __attribute__((ext_vector_type(4)));

// ---------------------------------------------------------------------------
// GEMM + attention source/dest terms fused:
//   H[n,:] = X[n,:] @ W ;  s[n] = H[n,:]·a_src ; d[n] = H[n,:]·a_dst
// Block: 256 threads, 16 rows. W tiles staged through LDS.
// ---------------------------------------------------------------------------
__global__ __launch_bounds__(256) void gemm_sd_kernel(
    const float* __restrict__ X,
    const int*   __restrict__ idx,
    const float* __restrict__ emb,
    const float* __restrict__ W,
    const float* __restrict__ a_src,
    const float* __restrict__ a_dst,
    float*       __restrict__ H,
    float*       __restrict__ s,
    float*       __restrict__ d)
{
    __shared__ __align__(16) float xs[16][FD];     // 16 KB
    __shared__ __align__(16) f4    wbuf[2048];     // 32 KB: W[32][256] tile
    const int tid = threadIdx.x;
    const int n0  = blockIdx.x * 16;

    #pragma unroll
    for (int r = 0; r < 16; ++r) {
        const float* src = idx ? (emb + (size_t)idx[n0 + r] * FD)
                               : (X + (size_t)(n0 + r) * FD);
        xs[r][tid] = src[tid];
    }

    const int wave = tid >> 6;
    const int lane = tid & 63;
    const int c0 = lane * 4;
    const int r0 = wave * 4;
    const f4* W4 = reinterpret_cast<const f4*>(W);

    float acc[4][4] = {};
    for (int st = 0; st < FD / 32; ++st) {
        #pragma unroll
        for (int p = 0; p < 8; ++p)
            wbuf[p * 256 + tid] = W4[st * 2048 + p * 256 + tid];
        __syncthreads();

        #pragma unroll 4
        for (int kk = 0; kk < 32; ++kk) {
            const int k = st * 32 + kk;
            f4 w = wbuf[kk * 64 + lane];
            #pragma unroll
            for (int r = 0; r < 4; ++r) {
                float x = xs[r0 + r][k];
                acc[r][0] = fmaf(x, w[0], acc[r][0]);
                acc[r][1] = fmaf(x, w[1], acc[r][1]);
                acc[r][2] = fmaf(x, w[2], acc[r][2]);
                acc[r][3] = fmaf(x, w[3], acc[r][3]);
            }
        }
        __syncthreads();
    }

    const float4 as4 = *reinterpret_cast<const float4*>(a_src + c0);
    const float4 ad4 = *reinterpret_cast<const float4*>(a_dst + c0);

    #pragma unroll
    for (int r = 0; r < 4; ++r) {
        float4 o = make_float4(acc[r][0], acc[r][1], acc[r][2], acc[r][3]);
        *reinterpret_cast<float4*>(H + (size_t)(n0 + r0 + r) * FD + c0) = o;

        float ps = acc[r][0]*as4.x + acc[r][1]*as4.y + acc[r][2]*as4.z + acc[r][3]*as4.w;
        float pd = acc[r][0]*ad4.x + acc[r][1]*ad4.y + acc[r][2]*ad4.z + acc[r][3]*ad4.w;
        #pragma unroll
        for (int off = 32; off > 0; off >>= 1) {
            ps += __shfl_xor(ps, off);
            pd += __shfl_xor(pd, off);
        }
        if (lane == 0) {
            s[n0 + r0 + r] = ps;
            d[n0 + r0 + r] = pd;
        }
    }
}

// ---------------------------------------------------------------------------
// Row-per-WAVE attention (R4 structure, L2-merged writes).
// 4 waves/block, wave owns a row, zero __syncthreads. Per row:
//   1. dense zero of the output row — NORMAL stores (L2-allocating, so the
//      later scatter merges in L2; drain waits L2-completion, not HBM)
//   2. stream 32 KB adj row (nt loads), ballot-compact nonzeros into LDS
//   3. softmax over the ~33-entry list (e = lrelu(s_i + d_j))
//   4. s_waitcnt vmcnt(0) (cheap now), scatter normalized probs (L2 merge)
//   5. aggregate out[i,:] = sum_k p_k * H[j_k,:]  (one f4/lane, 4-way ILP)
// Deterministic: ballot order, fixed-order shuffle reductions, serial t-loop.
// ---------------------------------------------------------------------------
__global__ __launch_bounds__(256, 6) void attn_kernel(
    const float* __restrict__ adj,
    const float* __restrict__ svec,
    const float* __restrict__ dvec,
    const float* __restrict__ H,
    const float* residual,          // may alias out_rows (row-local)
    float* __restrict__ attn_out,
    float* out_rows)
{
    __shared__ int   jbuf_s[4 * CAP];
    __shared__ float pbuf_s[4 * CAP];

    const int tid  = threadIdx.x;
    const int lane = tid & 63;
    const int wv   = tid >> 6;
    const int i    = blockIdx.x * 4 + wv;

    int*   jbuf = jbuf_s + wv * CAP;
    float* pbuf = pbuf_s + wv * CAP;

    // 1. dense zero of the output row (normal stores -> L2)
    f4* orow4 = reinterpret_cast<f4*>(attn_out + (size_t)i * NN);
    const f4 z = {0.f, 0.f, 0.f, 0.f};
    #pragma unroll
    for (int q = 0; q < 32; ++q)
        orow4[q * 64 + lane] = z;

    // 2. stream adj row (nt) + ballot compaction
    const f4* arow4 = reinterpret_cast<const f4*>(adj + (size_t)i * NN);
    const unsigned long long lt = (lane == 0) ? 0ull : (~0ull >> (64 - lane));
    int base = 0;
    #pragma unroll
    for (int c = 0; c < 8; ++c) {
        f4 av[4];
        #pragma unroll
        for (int k = 0; k < 4; ++k)
            av[k] = __builtin_nontemporal_load(&arow4[c * 256 + k * 64 + lane]);
        #pragma unroll
        for (int k = 0; k < 4; ++k) {
            #pragma unroll
            for (int q = 0; q < 4; ++q) {
                const bool nz = (av[k][q] != 0.f);
                const unsigned long long mask = __ballot(nz);
                if (nz) {
                    const int pos = base + (int)__popcll(mask & lt);
                    if (pos < CAP)
                        jbuf[pos] = (c * 1024) + (k * 256) + (lane * 4) + q;
                }
                base += (int)__popcll(mask);
            }
        }
    }
    const int nnz = (base < CAP) ? base : CAP;

    // 3. softmax over compacted list (shuffle-only)
    const float si = svec[i];
    float mloc = NEGF;
    for (int t = lane; t < nnz; t += 64) {
        float e = si + dvec[jbuf[t]];
        e = (e >= 0.f) ? e : LSLOPE * e;
        pbuf[t] = e;
        mloc = fmaxf(mloc, e);
    }
    #pragma unroll
    for (int off = 32; off > 0; off >>= 1) mloc = fmaxf(mloc, __shfl_xor(mloc, off));
    const float m = mloc;

    float sloc = 0.f;
    for (int t = lane; t < nnz; t += 64) {
        float p = __expf(pbuf[t] - m);
        pbuf[t] = p;
        sloc += p;
    }
    #pragma unroll
    for (int off = 32; off > 0; off >>= 1) sloc += __shfl_xor(sloc, off);
    const float inv = 1.f / sloc;

    // 4. drain zero-stores (L2-completion, cheap), scatter normalized probs
    asm volatile("s_waitcnt vmcnt(0)" ::: "memory");
    for (int t = lane; t < nnz; t += 64) {
        float pn = pbuf[t] * inv;
        pbuf[t] = pn;
        attn_out[(size_t)i * NN + jbuf[t]] = pn;
    }

    // 5. sparse aggregate: one f4 per lane covers all 256 cols, 4-way ILP
    const f4* H4 = reinterpret_cast<const f4*>(H);
    f4 a0 = {0.f, 0.f, 0.f, 0.f};
    f4 a1 = {0.f, 0.f, 0.f, 0.f};
    f4 a2 = {0.f, 0.f, 0.f, 0.f};
    f4 a3 = {0.f, 0.f, 0.f, 0.f};
    int t = 0;
    for (; t + 4 <= nnz; t += 4) {
        a0 += pbuf[t]     * H4[(size_t)jbuf[t]     * 64 + lane];
        a1 += pbuf[t + 1] * H4[(size_t)jbuf[t + 1] * 64 + lane];
        a2 += pbuf[t + 2] * H4[(size_t)jbuf[t + 2] * 64 + lane];
        a3 += pbuf[t + 3] * H4[(size_t)jbuf[t + 3] * 64 + lane];
    }
    for (; t < nnz; ++t)
        a0 += pbuf[t] * H4[(size_t)jbuf[t] * 64 + lane];
    f4 o = (a0 + a1) + (a2 + a3);
    if (residual)
        o += reinterpret_cast<const f4*>(residual)[(size_t)i * 64 + lane];
    reinterpret_cast<f4*>(out_rows)[(size_t)i * 64 + lane] = o;
}

// ---------------------------------------------------------------------------
// Column mean over 8192 rows, deterministic two-step
// ---------------------------------------------------------------------------
__global__ __launch_bounds__(256) void colsum_partial(
    const float* __restrict__ doc, float* __restrict__ partial)
{
    const int tid = threadIdx.x;
    const int b = blockIdx.x;            // 128 blocks x 64 rows
    float acc = 0.f;
    const float* p = doc + (size_t)b * 64 * FD + tid;
    #pragma unroll 8
    for (int r = 0; r < 64; ++r) acc += p[(size_t)r * FD];
    partial[b * FD + tid] = acc;
}

__global__ __launch_bounds__(256) void colsum_final(
    const float* __restrict__ partial, float* __restrict__ out)
{
    const int tid = threadIdx.x;
    float acc = 0.f;
    for (int b = 0; b < 128; ++b) acc += partial[b * FD + tid];
    out[tid] = acc * (1.f / (float)NN);
}

// ---------------------------------------------------------------------------
extern "C" void kernel_launch(void* const* d_in, const int* in_sizes, int n_in,
                              void* d_out, int out_size, void* d_ws, size_t ws_size,
                              hipStream_t stream)
{
    const int*   inDoc = (const int*)d_in[0];
    const float* adj0  = (const float*)d_in[1];
    const float* adj1  = (const float*)d_in[2];
    const float* emb   = (const float*)d_in[3];
    const float* W1    = (const float*)d_in[4];
    const float* a1s   = (const float*)d_in[5];
    const float* a1d   = (const float*)d_in[6];
    const float* W2    = (const float*)d_in[7];
    const float* a2s   = (const float*)d_in[8];
    const float* a2d   = (const float*)d_in[9];

    float* out     = (float*)d_out;
    float* docMean = out;
    float* sattn   = out + 256;
    float* dattn   = out + 256 + (size_t)NN * NN;

    float* ws = (float*)d_ws;
    float* h   = ws;                         // NN*FD (h1 then h2)
    float* o1  = ws + (size_t)NN * FD;       // NN*FD (out1, then document in-place)
    float* s1  = ws + 2 * (size_t)NN * FD;   // NN
    float* d1  = s1 + NN;                    // NN
    float* s2  = d1 + NN;                    // NN
    float* d2  = s2 + NN;                    // NN
    float* partial = d2 + NN;                // 128*FD

    // layer 1
    gemm_sd_kernel<<<NN / 16, 256, 0, stream>>>(nullptr, inDoc, emb, W1, a1s, a1d, h, s1, d1);
    attn_kernel<<<NN / 4, 256, 0, stream>>>(adj0, s1, d1, h, nullptr, sattn, o1);

    // layer 2 (document = out2 + out1 written in-place into o1; row-local)
    gemm_sd_kernel<<<NN / 16, 256, 0, stream>>>(o1, nullptr, nullptr, W2, a2s, a2d, h, s2, d2);
    attn_kernel<<<NN / 4, 256, 0, stream>>>(adj1, s2, d2, h, o1, dattn, o1);

    // docMean
    colsum_partial<<<128, 256, 0, stream>>>(o1, partial);
    colsum_final<<<1, 256, 0, stream>>>(partial, docMean);
}

// Round 8
// 296.353 us; speedup vs baseline: 1.1267x; 1.1267x over previous
//
#include <hip/hip_runtime.h>
#include <cstddef>

#define NN 8192
#define FD 256
#define LSLOPE 0.01f
#define NEGF -3.0e38f
#define CAP 96           // max nonzeros per row (avg 33, 11-sigma < 96)

typedef float f4 __attribute__((ext_vector_type(4)));

// ---------------------------------------------------------------------------
// GEMM + attention source/dest terms fused:
//   H[n,:] = X[n,:] @ W ;  s[n] = H[n,:]·a_src ; d[n] = H[n,:]·a_dst
// Block: 256 threads, 16 rows. W tiles staged through LDS.
// ---------------------------------------------------------------------------
__global__ __launch_bounds__(256) void gemm_sd_kernel(
    const float* __restrict__ X,
    const int*   __restrict__ idx,
    const float* __restrict__ emb,
    const float* __restrict__ W,
    const float* __restrict__ a_src,
    const float* __restrict__ a_dst,
    float*       __restrict__ H,
    float*       __restrict__ s,
    float*       __restrict__ d)
{
    __shared__ __align__(16) float xs[16][FD];     // 16 KB
    __shared__ __align__(16) f4    wbuf[2048];     // 32 KB: W[32][256] tile
    const int tid = threadIdx.x;
    const int n0  = blockIdx.x * 16;

    #pragma unroll
    for (int r = 0; r < 16; ++r) {
        const float* src = idx ? (emb + (size_t)idx[n0 + r] * FD)
                               : (X + (size_t)(n0 + r) * FD);
        xs[r][tid] = src[tid];
    }

    const int wave = tid >> 6;
    const int lane = tid & 63;
    const int c0 = lane * 4;
    const int r0 = wave * 4;
    const f4* W4 = reinterpret_cast<const f4*>(W);

    float acc[4][4] = {};
    for (int st = 0; st < FD / 32; ++st) {
        #pragma unroll
        for (int p = 0; p < 8; ++p)
            wbuf[p * 256 + tid] = W4[st * 2048 + p * 256 + tid];
        __syncthreads();

        #pragma unroll 4
        for (int kk = 0; kk < 32; ++kk) {
            const int k = st * 32 + kk;
            f4 w = wbuf[kk * 64 + lane];
            #pragma unroll
            for (int r = 0; r < 4; ++r) {
                float x = xs[r0 + r][k];
                acc[r][0] = fmaf(x, w[0], acc[r][0]);
                acc[r][1] = fmaf(x, w[1], acc[r][1]);
                acc[r][2] = fmaf(x, w[2], acc[r][2]);
                acc[r][3] = fmaf(x, w[3], acc[r][3]);
            }
        }
        __syncthreads();
    }

    const float4 as4 = *reinterpret_cast<const float4*>(a_src + c0);
    const float4 ad4 = *reinterpret_cast<const float4*>(a_dst + c0);

    #pragma unroll
    for (int r = 0; r < 4; ++r) {
        float4 o = make_float4(acc[r][0], acc[r][1], acc[r][2], acc[r][3]);
        *reinterpret_cast<float4*>(H + (size_t)(n0 + r0 + r) * FD + c0) = o;

        float ps = acc[r][0]*as4.x + acc[r][1]*as4.y + acc[r][2]*as4.z + acc[r][3]*as4.w;
        float pd = acc[r][0]*ad4.x + acc[r][1]*ad4.y + acc[r][2]*ad4.z + acc[r][3]*ad4.w;
        #pragma unroll
        for (int off = 32; off > 0; off >>= 1) {
            ps += __shfl_xor(ps, off);
            pd += __shfl_xor(pd, off);
        }
        if (lane == 0) {
            s[n0 + r0 + r] = ps;
            d[n0 + r0 + r] = pd;
        }
    }
}

// ---------------------------------------------------------------------------
// Attention COMPUTE (kernel A): row-per-wave, pure READ stream. Per row:
//   1. stream 32 KB adj row (nt loads), ballot-compact nonzeros into LDS
//   2. softmax over the ~33-entry list (e = lrelu(s_i + d_j))
//   3. store compact (j, p*inv) list + nnz to workspace (dense write deferred
//      to the direction-pure expand kernel)
//   4. aggregate out[i,:] = sum_k p_k * H[j_k,:]  (one f4/lane, 4-way ILP)
// No dense write, no zero-fill, no vmcnt drain, zero __syncthreads.
// Deterministic: ballot order, fixed-order shuffle reductions, serial t-loop.
// ---------------------------------------------------------------------------
__global__ __launch_bounds__(256, 6) void attn_compute_kernel(
    const float* __restrict__ adj,
    const float* __restrict__ svec,
    const float* __restrict__ dvec,
    const float* __restrict__ H,
    const float* residual,          // may alias out_rows (row-local)
    float* __restrict__ out_rows,
    int*   __restrict__ jw,         // [2*NN][CAP]
    float* __restrict__ pw,         // [2*NN][CAP]
    int*   __restrict__ nnzw,       // [2*NN]
    int list_base)
{
    __shared__ int   jbuf_s[4 * CAP];
    __shared__ float pbuf_s[4 * CAP];

    const int tid  = threadIdx.x;
    const int lane = tid & 63;
    const int wv   = tid >> 6;
    const int i    = blockIdx.x * 4 + wv;

    int*   jbuf = jbuf_s + wv * CAP;
    float* pbuf = pbuf_s + wv * CAP;

    // 1. stream adj row (nt) + ballot compaction
    const f4* arow4 = reinterpret_cast<const f4*>(adj + (size_t)i * NN);
    const unsigned long long lt = (lane == 0) ? 0ull : (~0ull >> (64 - lane));
    int base = 0;
    #pragma unroll
    for (int c = 0; c < 8; ++c) {
        f4 av[4];
        #pragma unroll
        for (int k = 0; k < 4; ++k)
            av[k] = __builtin_nontemporal_load(&arow4[c * 256 + k * 64 + lane]);
        #pragma unroll
        for (int k = 0; k < 4; ++k) {
            #pragma unroll
            for (int q = 0; q < 4; ++q) {
                const bool nz = (av[k][q] != 0.f);
                const unsigned long long mask = __ballot(nz);
                if (nz) {
                    const int pos = base + (int)__popcll(mask & lt);
                    if (pos < CAP)
                        jbuf[pos] = (c * 1024) + (k * 256) + (lane * 4) + q;
                }
                base += (int)__popcll(mask);
            }
        }
    }
    const int nnz = (base < CAP) ? base : CAP;

    // 2. softmax over compacted list (shuffle-only)
    const float si = svec[i];
    float mloc = NEGF;
    for (int t = lane; t < nnz; t += 64) {
        float e = si + dvec[jbuf[t]];
        e = (e >= 0.f) ? e : LSLOPE * e;
        pbuf[t] = e;
        mloc = fmaxf(mloc, e);
    }
    #pragma unroll
    for (int off = 32; off > 0; off >>= 1) mloc = fmaxf(mloc, __shfl_xor(mloc, off));
    const float m = mloc;

    float sloc = 0.f;
    for (int t = lane; t < nnz; t += 64) {
        float p = __expf(pbuf[t] - m);
        pbuf[t] = p;
        sloc += p;
    }
    #pragma unroll
    for (int off = 32; off > 0; off >>= 1) sloc += __shfl_xor(sloc, off);
    const float inv = 1.f / sloc;

    // 3. store compact list (normalized) + header
    const size_t lrow = (size_t)(list_base + i) * CAP;
    for (int t = lane; t < nnz; t += 64) {
        jw[lrow + t] = jbuf[t];
        pw[lrow + t] = pbuf[t] * inv;
    }
    if (lane == 0) nnzw[list_base + i] = nnz;

    // 4. sparse aggregate: one f4 per lane covers all 256 cols, 4-way ILP
    const f4* H4 = reinterpret_cast<const f4*>(H);
    f4 a0 = {0.f, 0.f, 0.f, 0.f};
    f4 a1 = {0.f, 0.f, 0.f, 0.f};
    f4 a2 = {0.f, 0.f, 0.f, 0.f};
    f4 a3 = {0.f, 0.f, 0.f, 0.f};
    int t = 0;
    for (; t + 4 <= nnz; t += 4) {
        a0 += pbuf[t]     * H4[(size_t)jbuf[t]     * 64 + lane];
        a1 += pbuf[t + 1] * H4[(size_t)jbuf[t + 1] * 64 + lane];
        a2 += pbuf[t + 2] * H4[(size_t)jbuf[t + 2] * 64 + lane];
        a3 += pbuf[t + 3] * H4[(size_t)jbuf[t + 3] * 64 + lane];
    }
    for (; t < nnz; ++t)
        a0 += pbuf[t] * H4[(size_t)jbuf[t] * 64 + lane];
    f4 o = ((a0 + a1) + (a2 + a3)) * inv;
    if (residual)
        o += reinterpret_cast<const f4*>(residual)[(size_t)i * 64 + lane];
    reinterpret_cast<f4*>(out_rows)[(size_t)i * 64 + lane] = o;
}

// ---------------------------------------------------------------------------
// Attention EXPAND (kernel B): pure WRITE stream for BOTH layers.
// One block per dense output row: zero 32 KB LDS row, LDS-scatter the compact
// list, stream the row out with nt f4 stores (full lines, exactly once).
// ---------------------------------------------------------------------------
__global__ __launch_bounds__(256) void attn_expand_kernel(
    const int*   __restrict__ jw,
    const float* __restrict__ pw,
    const int*   __restrict__ nnzw,
    float* __restrict__ sattn,
    float* __restrict__ dattn)
{
    __shared__ __align__(16) float rbuf[NN];       // 32 KB
    const int tid = threadIdx.x;
    const int row = blockIdx.x;                    // 0..2*NN-1

    f4* r4 = reinterpret_cast<f4*>(rbuf);
    const f4 z = {0.f, 0.f, 0.f, 0.f};
    #pragma unroll
    for (int g = 0; g < 8; ++g)
        r4[g * 256 + tid] = z;
    __syncthreads();

    const int nnz = nnzw[row];
    const size_t lrow = (size_t)row * CAP;
    for (int t = tid; t < nnz; t += 256)
        rbuf[jw[lrow + t]] = pw[lrow + t];
    __syncthreads();

    float* outp = (row < NN) ? (sattn + (size_t)row * NN)
                             : (dattn + (size_t)(row - NN) * NN);
    f4* o4 = reinterpret_cast<f4*>(outp);
    #pragma unroll
    for (int g = 0; g < 8; ++g)
        __builtin_nontemporal_store(r4[g * 256 + tid], &o4[g * 256 + tid]);
}

// ---------------------------------------------------------------------------
// Column mean over 8192 rows, deterministic two-step
// ---------------------------------------------------------------------------
__global__ __launch_bounds__(256) void colsum_partial(
    const float* __restrict__ doc, float* __restrict__ partial)
{
    const int tid = threadIdx.x;
    const int b = blockIdx.x;            // 128 blocks x 64 rows
    float acc = 0.f;
    const float* p = doc + (size_t)b * 64 * FD + tid;
    #pragma unroll 8
    for (int r = 0; r < 64; ++r) acc += p[(size_t)r * FD];
    partial[b * FD + tid] = acc;
}

__global__ __launch_bounds__(256) void colsum_final(
    const float* __restrict__ partial, float* __restrict__ out)
{
    const int tid = threadIdx.x;
    float acc = 0.f;
    for (int b = 0; b < 128; ++b) acc += partial[b * FD + tid];
    out[tid] = acc * (1.f / (float)NN);
}

// ---------------------------------------------------------------------------
extern "C" void kernel_launch(void* const* d_in, const int* in_sizes, int n_in,
                              void* d_out, int out_size, void* d_ws, size_t ws_size,
                              hipStream_t stream)
{
    const int*   inDoc = (const int*)d_in[0];
    const float* adj0  = (const float*)d_in[1];
    const float* adj1  = (const float*)d_in[2];
    const float* emb   = (const float*)d_in[3];
    const float* W1    = (const float*)d_in[4];
    const float* a1s   = (const float*)d_in[5];
    const float* a1d   = (const float*)d_in[6];
    const float* W2    = (const float*)d_in[7];
    const float* a2s   = (const float*)d_in[8];
    const float* a2d   = (const float*)d_in[9];

    float* out     = (float*)d_out;
    float* docMean = out;
    float* sattn   = out + 256;
    float* dattn   = out + 256 + (size_t)NN * NN;

    float* ws = (float*)d_ws;
    float* h   = ws;                         // NN*FD (h1 then h2)
    float* o1  = ws + (size_t)NN * FD;       // NN*FD (out1, then document in-place)
    float* s1  = ws + 2 * (size_t)NN * FD;   // NN
    float* d1  = s1 + NN;                    // NN
    float* s2  = d1 + NN;                    // NN
    float* d2  = s2 + NN;                    // NN
    float* partial = d2 + NN;                // 128*FD
    float* pw  = partial + 128 * FD;         // 2*NN*CAP floats
    int*   jw  = (int*)(pw + (size_t)2 * NN * CAP);   // 2*NN*CAP ints
    int*   nnzw = (int*)(jw + (size_t)2 * NN * CAP);  // 2*NN ints

    // layer 1
    gemm_sd_kernel<<<NN / 16, 256, 0, stream>>>(nullptr, inDoc, emb, W1, a1s, a1d, h, s1, d1);
    attn_compute_kernel<<<NN / 4, 256, 0, stream>>>(adj0, s1, d1, h, nullptr, o1,
                                                    jw, pw, nnzw, 0);

    // layer 2 (document = out2 + out1 written in-place into o1; row-local)
    gemm_sd_kernel<<<NN / 16, 256, 0, stream>>>(o1, nullptr, nullptr, W2, a2s, a2d, h, s2, d2);
    attn_compute_kernel<<<NN / 4, 256, 0, stream>>>(adj1, s2, d2, h, o1, o1,
                                                    jw, pw, nnzw, NN);

    // docMean
    colsum_partial<<<128, 256, 0, stream>>>(o1, partial);
    colsum_final<<<1, 256, 0, stream>>>(partial, docMean);

    // direction-pure dense write of both attention matrices (537 MB stream)
    attn_expand_kernel<<<2 * NN, 256, 0, stream>>>(jw, pw, nnzw, sattn, dattn);
}